// Round 7
// baseline (194.096 us; speedup 1.0000x reference)
//
#include <hip/hip_runtime.h>

#define NN 16384
#define NE 262144

// ---------------------------------------------------------------------------
// prep: per layer. One wave per node.
//  - G[v][s][o] = sum_i h[v][i] * Ws[i*32+o], s=0..7 from Wk, s=8 from bk
//  - agg[v][o]  = sum_i h[v][i] * root[i*32+o] + b[o]   (edge pass adds on top)
// ---------------------------------------------------------------------------
__global__ __launch_bounds__(256) void prep_kernel(
    const float* __restrict__ hin, int in_stride, int apply_relu,
    const float* __restrict__ Wk, const float* __restrict__ bk,
    const float* __restrict__ root, const float* __restrict__ bvec,
    float* __restrict__ G, float* __restrict__ agg, int n)
{
    int gtid = blockIdx.x * blockDim.x + threadIdx.x;
    int wid  = gtid >> 6;
    int nw   = (gridDim.x * blockDim.x) >> 6;
    int lane = threadIdx.x & 63;
    int o    = lane & 31;
    int half = lane >> 5;

    float w[5][32];
#pragma unroll
    for (int k = 0; k < 5; ++k) {
        int s = half * 5 + k;
        const float* Ws = (s < 8) ? (Wk + s * 1024) : ((s == 8) ? bk : root);
#pragma unroll
        for (int i = 0; i < 32; ++i) w[k][i] = Ws[i * 32 + o];
    }
    float bo = bvec[o];

    for (int v = wid; v < n; v += nw) {
        float hv = hin[(size_t)v * in_stride + o];
        if (apply_relu) hv = fmaxf(hv, 0.0f);
        float acc0 = 0.f, acc1 = 0.f, acc2 = 0.f, acc3 = 0.f, acc4 = 0.f;
#pragma unroll
        for (int i = 0; i < 32; ++i) {
            float hi = __shfl(hv, i, 64);
            acc0 = fmaf(hi, w[0][i], acc0);
            acc1 = fmaf(hi, w[1][i], acc1);
            acc2 = fmaf(hi, w[2][i], acc2);
            acc3 = fmaf(hi, w[3][i], acc3);
            acc4 = fmaf(hi, w[4][i], acc4);
        }
        float* Gv = G + (size_t)v * 288;
        if (half == 0) {
            Gv[0 * 32 + o] = acc0;
            Gv[1 * 32 + o] = acc1;
            Gv[2 * 32 + o] = acc2;
            Gv[3 * 32 + o] = acc3;
            Gv[4 * 32 + o] = acc4;
        } else {
            Gv[5 * 32 + o] = acc0;
            Gv[6 * 32 + o] = acc1;
            Gv[7 * 32 + o] = acc2;
            Gv[8 * 32 + o] = acc3;               // bias slice
            agg[(size_t)v * 32 + o] = acc4 + bo; // root product + b
        }
    }
}

// ---------------------------------------------------------------------------
// CSR-by-tgt build (rebuilt every call; deterministic work).
// ---------------------------------------------------------------------------
__global__ __launch_bounds__(256) void zero_misc(int* __restrict__ cnt,
                                                 float* __restrict__ pooled)
{
    int i = blockIdx.x * blockDim.x + threadIdx.x;
    if (i < NN) cnt[i] = 0;
    if (i < 32) pooled[i] = 0.0f;
}

__global__ __launch_bounds__(256) void hist_kernel(const int* __restrict__ key,
                                                   int* __restrict__ cnt)
{
    int i = blockIdx.x * blockDim.x + threadIdx.x;
    if (i < NE) atomicAdd(&cnt[key[i]], 1);
}

// single-block exclusive scan of cnt[0..NN) -> offs[0..NN]; zeroes cnt.
__global__ __launch_bounds__(1024) void scan_kernel(int* __restrict__ cnt,
                                                    int* __restrict__ offs)
{
    __shared__ int a[1024], b[1024];
    int t = threadIdx.x;
    int base = t * 16;
    int local[16];
    int s = 0;
#pragma unroll
    for (int j = 0; j < 16; ++j) { local[j] = s; s += cnt[base + j]; }
    a[t] = s;
    __syncthreads();
    int* in  = a;
    int* out = b;
    for (int off = 1; off < 1024; off <<= 1) {
        out[t] = in[t] + ((t >= off) ? in[t - off] : 0);
        __syncthreads();
        int* tmp = in; in = out; out = tmp;
    }
    int excl = (t == 0) ? 0 : in[t - 1];
#pragma unroll
    for (int j = 0; j < 16; ++j) { offs[base + j] = excl + local[j]; cnt[base + j] = 0; }
    if (t == 1023) offs[NN] = in[1023];
}

// light scatter: one 8B write per edge (src node + edge id); e stays in place.
__global__ __launch_bounds__(256) void scatter_idx_kernel(
    const int* __restrict__ src, const int* __restrict__ tgt,
    const int* __restrict__ offs, int* __restrict__ cnt,
    int2* __restrict__ pair_s)
{
    int i = blockIdx.x * blockDim.x + threadIdx.x;
    if (i < NE) {
        int tv = tgt[i];
        int pos = offs[tv] + atomicAdd(&cnt[tv], 1);
        pair_s[pos] = make_int2(src[i], i);
    }
}

// ---------------------------------------------------------------------------
// tgt-major aggregation: half-wave per tgt node; register accumulation; NO
// atomics. Per in-edge: gather G[src] (9 x 128B coalesced), e[eid] broadcast.
// ---------------------------------------------------------------------------
__global__ __launch_bounds__(256) void agg_tgt_kernel(
    const float* __restrict__ efeat, const int2* __restrict__ pair_s,
    const int* __restrict__ offs, const float* __restrict__ G,
    float* __restrict__ agg, int n)
{
    int gtid = blockIdx.x * blockDim.x + threadIdx.x;
    int o    = gtid & 31;
    int hw   = gtid >> 5;
    int nhw  = (gridDim.x * blockDim.x) >> 5;

    for (int v = hw; v < n; v += nhw) {
        int beg = offs[v];
        int end = offs[v + 1];
        float acc = agg[(size_t)v * 32 + o];   // root + bias from prep
        for (int ed = beg; ed < end; ++ed) {
            int2 p = pair_s[ed];
            const float4* pe = (const float4*)(efeat + (size_t)p.y * 8);
            float4 ea = pe[0];
            float4 eb = pe[1];
            const float* g = G + (size_t)p.x * 288;
            float m = g[8 * 32 + o];
            m = fmaf(ea.x, g[0 * 32 + o], m);
            m = fmaf(ea.y, g[1 * 32 + o], m);
            m = fmaf(ea.z, g[2 * 32 + o], m);
            m = fmaf(ea.w, g[3 * 32 + o], m);
            m = fmaf(eb.x, g[4 * 32 + o], m);
            m = fmaf(eb.y, g[5 * 32 + o], m);
            m = fmaf(eb.z, g[6 * 32 + o], m);
            m = fmaf(eb.w, g[7 * 32 + o], m);
            acc += m;
        }
        agg[(size_t)v * 32 + o] = acc;         // exclusive owner: plain store
    }
}

// pool: pooled[o] = sum_v relu(agg[v][o])
__global__ __launch_bounds__(256) void pool_kernel(
    const float* __restrict__ agg, float* __restrict__ pooled, int n)
{
    int gtid  = blockIdx.x * blockDim.x + threadIdx.x;
    int o     = gtid & 31;
    int row0  = gtid >> 5;
    int nrows = (gridDim.x * blockDim.x) >> 5;
    float sum = 0.0f;
    for (int v = row0; v < n; v += nrows)
        sum += fmaxf(agg[(size_t)v * 32 + o], 0.0f);
    sum += __shfl_xor(sum, 32, 64);
    if ((threadIdx.x & 63) < 32) atomicAdd(pooled + o, sum);
}

__global__ void final_kernel(const float* __restrict__ pooled,
                             const float* __restrict__ Wd,
                             const float* __restrict__ bd,
                             float* __restrict__ out)
{
    int lane = threadIdx.x;
    float v = (lane < 32) ? pooled[lane] * Wd[lane] : 0.0f;
#pragma unroll
    for (int k = 32; k >= 1; k >>= 1) v += __shfl_xor(v, k, 64);
    if (lane == 0) out[0] = fmaxf(v + bd[0], 0.0f);
}

extern "C" void kernel_launch(void* const* d_in, const int* in_sizes, int n_in,
                              void* d_out, int out_size, void* d_ws, size_t ws_size,
                              hipStream_t stream)
{
    const float* x     = (const float*)d_in[0];
    const int*   src   = (const int*)d_in[1];
    const int*   tgt   = (const int*)d_in[2];
    const float* e     = (const float*)d_in[3];
    const float* Wk1   = (const float*)d_in[4];
    const float* bk1   = (const float*)d_in[5];
    const float* root1 = (const float*)d_in[6];
    const float* b1    = (const float*)d_in[7];
    const float* Wk2   = (const float*)d_in[8];
    const float* bk2   = (const float*)d_in[9];
    const float* root2 = (const float*)d_in[10];
    const float* b2    = (const float*)d_in[11];
    const float* Wd    = (const float*)d_in[12];
    const float* bd    = (const float*)d_in[13];
    float* out = (float*)d_out;

    // workspace layout (256B-aligned blocks):
    char* ws = (char*)d_ws;
    size_t off = 0;
    float* agg    = (float*)(ws + off); off += (size_t)NN * 32 * 4;      // 2 MB
    float* pooled = (float*)(ws + off); off += 256;
    float* G      = (float*)(ws + off); off += (size_t)NN * 288 * 4;     // 18.9 MB
    int*   cnt    = (int*)  (ws + off); off += (size_t)NN * 4;           // 64 KB
    int*   offs   = (int*)  (ws + off); off += ((size_t)NN + 64) * 4;    // 64 KB+
    int2*  pair_s = (int2*) (ws + off); off += (size_t)NE * 8;           // 2 MB

    // CSR-by-tgt build (used by both layers)
    zero_misc<<<64, 256, 0, stream>>>(cnt, pooled);
    hist_kernel<<<1024, 256, 0, stream>>>(tgt, cnt);
    scan_kernel<<<1, 1024, 0, stream>>>(cnt, offs);
    scatter_idx_kernel<<<1024, 256, 0, stream>>>(src, tgt, offs, cnt, pair_s);

    // layer 1
    prep_kernel<<<512, 256, 0, stream>>>(x, 33, 0, Wk1, bk1, root1, b1, G, agg, NN);
    agg_tgt_kernel<<<2048, 256, 0, stream>>>(e, pair_s, offs, G, agg, NN);

    // layer 2 (relu on load; in-place agg rewrite is same-half-wave safe)
    prep_kernel<<<512, 256, 0, stream>>>(agg, 32, 1, Wk2, bk2, root2, b2, G, agg, NN);
    agg_tgt_kernel<<<2048, 256, 0, stream>>>(e, pair_s, offs, G, agg, NN);

    // pool + final
    pool_kernel<<<64, 256, 0, stream>>>(agg, pooled, NN);
    final_kernel<<<1, 64, 0, stream>>>(pooled, Wd, bd, out);
}

// Round 8
// 120.170 us; speedup vs baseline: 1.6152x; 1.6152x over previous
//
#include <hip/hip_runtime.h>

#define NN 16384
#define NE 262144
#define NBUCKET 8
#define BUCKET_SHIFT 11          // 16384/8 = 2048 nodes per bucket
#define BUCKET_SZ 2048

// ---------------------------------------------------------------------------
// prep: per layer, XCD-bucketed (block b handles node bucket b&7 so G rows are
// produced in the same XCD's L2 that will consume them in edge_kernel).
//  - G[v][s][o] = sum_i h[v][i] * Ws[i*32+o], s=0..7 from Wk, s=8 from bk
//  - agg[v][o]  = sum_i h[v][i] * root[i*32+o] + b[o]
// Also zeroes pooled/ticket (needed before poolfinal; idempotent).
// ---------------------------------------------------------------------------
__global__ __launch_bounds__(256) void prep_kernel(
    const float* __restrict__ hin, int in_stride, int apply_relu,
    const float* __restrict__ Wk, const float* __restrict__ bk,
    const float* __restrict__ root, const float* __restrict__ bvec,
    float* __restrict__ G, float* __restrict__ agg,
    float* __restrict__ pooled, int* __restrict__ ticket)
{
    if (blockIdx.x == 0 && threadIdx.x < 33) {
        if (threadIdx.x < 32) pooled[threadIdx.x] = 0.0f;
        else *ticket = 0;
    }

    int lane = threadIdx.x & 63;
    int o    = lane & 31;
    int half = lane >> 5;

    int bucket = blockIdx.x & 7;
    int wave_in_b  = (blockIdx.x >> 3) * (blockDim.x >> 6) + (threadIdx.x >> 6);
    int waves_per_b = (gridDim.x >> 3) * (blockDim.x >> 6);

    float w[5][32];
#pragma unroll
    for (int k = 0; k < 5; ++k) {
        int s = half * 5 + k;
        const float* Ws = (s < 8) ? (Wk + s * 1024) : ((s == 8) ? bk : root);
#pragma unroll
        for (int i = 0; i < 32; ++i) w[k][i] = Ws[i * 32 + o];
    }
    float bo = bvec[o];

    int vend = (bucket + 1) * BUCKET_SZ;
    for (int v = bucket * BUCKET_SZ + wave_in_b; v < vend; v += waves_per_b) {
        float hv = hin[(size_t)v * in_stride + o];
        if (apply_relu) hv = fmaxf(hv, 0.0f);
        float acc0 = 0.f, acc1 = 0.f, acc2 = 0.f, acc3 = 0.f, acc4 = 0.f;
#pragma unroll
        for (int i = 0; i < 32; ++i) {
            float hi = __shfl(hv, i, 64);
            acc0 = fmaf(hi, w[0][i], acc0);
            acc1 = fmaf(hi, w[1][i], acc1);
            acc2 = fmaf(hi, w[2][i], acc2);
            acc3 = fmaf(hi, w[3][i], acc3);
            acc4 = fmaf(hi, w[4][i], acc4);
        }
        float* Gv = G + (size_t)v * 288;
        if (half == 0) {
            Gv[0 * 32 + o] = acc0;
            Gv[1 * 32 + o] = acc1;
            Gv[2 * 32 + o] = acc2;
            Gv[3 * 32 + o] = acc3;
            Gv[4 * 32 + o] = acc4;
        } else {
            Gv[5 * 32 + o] = acc0;
            Gv[6 * 32 + o] = acc1;
            Gv[7 * 32 + o] = acc2;
            Gv[8 * 32 + o] = acc3;               // bias slice
            agg[(size_t)v * 32 + o] = acc4 + bo; // root product + b
        }
    }
}

// ---------------------------------------------------------------------------
// edge pass, XCD-bucket-filtered, no CSR. Each wave scans 64 edges at a time
// (coalesced src/tgt loads, one edge per lane), ballots for "src in my
// bucket", then processes hits two at a time (half-wave per edge: 32 lanes =
// 32 outputs). G reads stay inside this XCD's L2 slice. One atomicAdd per
// edge-output to agg[tgt].
// ---------------------------------------------------------------------------
__global__ __launch_bounds__(256) void edge_kernel(
    const float* __restrict__ efeat, const int* __restrict__ src,
    const int* __restrict__ tgt, const float* __restrict__ G,
    float* __restrict__ agg)
{
    int lane = threadIdx.x & 63;
    int o    = lane & 31;
    int half = lane >> 5;

    int bucket = blockIdx.x & 7;
    int wave_in_b  = (blockIdx.x >> 3) * (blockDim.x >> 6) + (threadIdx.x >> 6);
    int waves_per_b = (gridDim.x >> 3) * (blockDim.x >> 6);

    const int ngroups = NE / 64;
    for (int grp = wave_in_b; grp < ngroups; grp += waves_per_b) {
        int ebase = grp * 64;
        int my_src = src[ebase + lane];
        int my_tgt = tgt[ebase + lane];
        unsigned long long ball = __ballot((my_src >> BUCKET_SHIFT) == bucket);
        while (ball) {
            int j0 = __ffsll(ball) - 1;
            ball &= ball - 1;
            int j1 = -1;
            if (ball) { j1 = __ffsll(ball) - 1; ball &= ball - 1; }
            int ej = half ? j1 : j0;
            bool active = (ej >= 0);
            int sj = active ? ej : 0;
            int s_v = __shfl(my_src, sj, 64);
            int t_v = __shfl(my_tgt, sj, 64);
            if (active) {
                const float4* pe = (const float4*)(efeat + (size_t)(ebase + ej) * 8);
                float4 ea = pe[0];
                float4 eb = pe[1];
                const float* g = G + (size_t)s_v * 288;
                float m = g[8 * 32 + o];
                m = fmaf(ea.x, g[0 * 32 + o], m);
                m = fmaf(ea.y, g[1 * 32 + o], m);
                m = fmaf(ea.z, g[2 * 32 + o], m);
                m = fmaf(ea.w, g[3 * 32 + o], m);
                m = fmaf(eb.x, g[4 * 32 + o], m);
                m = fmaf(eb.y, g[5 * 32 + o], m);
                m = fmaf(eb.z, g[6 * 32 + o], m);
                m = fmaf(eb.w, g[7 * 32 + o], m);
                atomicAdd(agg + (size_t)t_v * 32 + o, m);
            }
        }
    }
}

// ---------------------------------------------------------------------------
// fused pool + final: pooled[o] = sum_v relu(agg[v][o]) via per-block partials
// + atomics; last block (ticket) computes out = relu(pooled . Wd + bd).
// ---------------------------------------------------------------------------
__global__ __launch_bounds__(256) void poolfinal_kernel(
    const float* __restrict__ agg, const float* __restrict__ Wd,
    const float* __restrict__ bd, float* __restrict__ pooled,
    int* __restrict__ ticket, float* __restrict__ out)
{
    int gtid  = blockIdx.x * blockDim.x + threadIdx.x;
    int o     = gtid & 31;
    int row0  = gtid >> 5;
    int nrows = (gridDim.x * blockDim.x) >> 5;
    float sum = 0.0f;
    for (int v = row0; v < NN; v += nrows)
        sum += fmaxf(agg[(size_t)v * 32 + o], 0.0f);
    sum += __shfl_xor(sum, 32, 64);
    if ((threadIdx.x & 63) < 32) atomicAdd(pooled + o, sum);
    __threadfence();
    __syncthreads();

    __shared__ int last;
    if (threadIdx.x == 0) {
        int old = atomicAdd(ticket, 1);
        last = (old == (int)gridDim.x - 1) ? 1 : 0;
    }
    __syncthreads();
    if (last && threadIdx.x < 64) {
        float pv = 0.0f;
        if (threadIdx.x < 32)
            pv = atomicAdd(pooled + threadIdx.x, 0.0f) * Wd[threadIdx.x];
#pragma unroll
        for (int k = 32; k >= 1; k >>= 1) pv += __shfl_xor(pv, k, 64);
        if (threadIdx.x == 0) out[0] = fmaxf(pv + bd[0], 0.0f);
    }
}

extern "C" void kernel_launch(void* const* d_in, const int* in_sizes, int n_in,
                              void* d_out, int out_size, void* d_ws, size_t ws_size,
                              hipStream_t stream)
{
    const float* x     = (const float*)d_in[0];
    const int*   src   = (const int*)d_in[1];
    const int*   tgt   = (const int*)d_in[2];
    const float* e     = (const float*)d_in[3];
    const float* Wk1   = (const float*)d_in[4];
    const float* bk1   = (const float*)d_in[5];
    const float* root1 = (const float*)d_in[6];
    const float* b1    = (const float*)d_in[7];
    const float* Wk2   = (const float*)d_in[8];
    const float* bk2   = (const float*)d_in[9];
    const float* root2 = (const float*)d_in[10];
    const float* b2    = (const float*)d_in[11];
    const float* Wd    = (const float*)d_in[12];
    const float* bd    = (const float*)d_in[13];
    float* out = (float*)d_out;

    // workspace: agg (2 MB) | pooled (32 f32) + ticket | G (18.9 MB)
    char* ws = (char*)d_ws;
    float* agg    = (float*)ws;
    float* pooled = (float*)(ws + (size_t)NN * 32 * 4);
    int*   ticket = (int*)  (ws + (size_t)NN * 32 * 4 + 32 * 4);
    float* G      = (float*)(ws + (size_t)NN * 32 * 4 + 256);

    // layer 1 (prep also zeroes pooled/ticket)
    prep_kernel<<<512, 256, 0, stream>>>(x, 33, 0, Wk1, bk1, root1, b1, G, agg, pooled, ticket);
    edge_kernel<<<2048, 256, 0, stream>>>(e, src, tgt, G, agg);

    // layer 2 (relu on load; in-place agg rewrite is same-wave safe)
    prep_kernel<<<512, 256, 0, stream>>>(agg, 32, 1, Wk2, bk2, root2, b2, G, agg, pooled, ticket);
    edge_kernel<<<2048, 256, 0, stream>>>(e, src, tgt, G, agg);

    // fused pool + final
    poolfinal_kernel<<<64, 256, 0, stream>>>(agg, Wd, bd, pooled, ticket, out);
}